// Round 10
// baseline (693.247 us; speedup 1.0000x reference)
//
#include <hip/hip_runtime.h>
#include <hip/hip_bf16.h>

#define IN_F  128
#define HID_F 256
#define OUT_F 64
#define BUCKET_SHIFT 9
#define BUCKET_SZ 512
#define EPB 8192            // edges per binning block

typedef __attribute__((ext_vector_type(8))) short bf16x8;
typedef __attribute__((ext_vector_type(4))) float f32x4;

__device__ __forceinline__ float bf2f(unsigned short u) {
    union { unsigned int i; float f; } v; v.i = ((unsigned int)u) << 16; return v.f;
}
__device__ __forceinline__ float bf2f_lo(unsigned int p) {
    union { unsigned int i; float f; } v; v.i = p << 16; return v.f;
}
__device__ __forceinline__ float bf2f_hi(unsigned int p) {
    union { unsigned int i; float f; } v; v.i = p & 0xffff0000u; return v.f;
}
__device__ __forceinline__ unsigned short f2bf(float f) {
    __hip_bfloat16 b = __float2bfloat16(f);
    return *reinterpret_cast<unsigned short*>(&b);
}

// ---- x fp32 -> bf16 (8 elems/thread) ------------------------------------
__global__ __launch_bounds__(256) void k_xconv(
    const float* __restrict__ x, unsigned short* __restrict__ xb, long long total8)
{
    long long i = (long long)blockIdx.x * blockDim.x + threadIdx.x;
    if (i >= total8) return;
    const float4* p = reinterpret_cast<const float4*>(x) + i * 2;
    float4 a = p[0], b = p[1];
    ushort4 o0, o1;
    o0.x = f2bf(a.x); o0.y = f2bf(a.y); o0.z = f2bf(a.z); o0.w = f2bf(a.w);
    o1.x = f2bf(b.x); o1.y = f2bf(b.y); o1.z = f2bf(b.z); o1.w = f2bf(b.w);
    reinterpret_cast<ushort4*>(xb)[i * 2]     = o0;
    reinterpret_cast<ushort4*>(xb)[i * 2 + 1] = o1;
}

// ---- CSR build via bucketed multisplit (no global per-edge atomics) -----
__global__ __launch_bounds__(256) void k_hist(
    const int* __restrict__ dst, int* __restrict__ counts,
    int nEdges, int NB)
{
    __shared__ int hist[256];
    int t = threadIdx.x;
    hist[t] = 0;
    __syncthreads();
    long long base = (long long)blockIdx.x * EPB;
    #pragma unroll
    for (int k = 0; k < EPB / 256; ++k) {
        long long e = base + k * 256 + t;
        if (e < nEdges) atomicAdd(&hist[dst[e] >> BUCKET_SHIFT], 1);
    }
    __syncthreads();
    if (t < NB) counts[t * gridDim.x + blockIdx.x] = hist[t];
}

__global__ __launch_bounds__(256) void k_btot(
    const int* __restrict__ counts, int* __restrict__ btot, int A)
{
    __shared__ int sh[256];
    int b = blockIdx.x, t = threadIdx.x;
    int s = 0;
    for (int i = t; i < A; i += 256) s += counts[(size_t)b * A + i];
    sh[t] = s; __syncthreads();
    for (int d = 128; d > 0; d >>= 1) {
        if (t < d) sh[t] += sh[t + d];
        __syncthreads();
    }
    if (t == 0) btot[b] = sh[0];
}

__global__ __launch_bounds__(256) void k_scanNB(
    const int* __restrict__ btot, int* __restrict__ bucketBase,
    int* __restrict__ rowptr, int NB, int nNodes, int nEdges)
{
    __shared__ int sh[256];
    int t = threadIdx.x;
    int v = (t < NB) ? btot[t] : 0;
    sh[t] = v; __syncthreads();
    for (int d = 1; d < 256; d <<= 1) {
        int add = (t >= d) ? sh[t - d] : 0;
        __syncthreads();
        sh[t] += add;
        __syncthreads();
    }
    if (t < NB) bucketBase[t] = sh[t] - v;
    if (t == 0) { bucketBase[NB] = nEdges; rowptr[nNodes] = nEdges; }
}

__global__ __launch_bounds__(256) void k_cursor(
    int* __restrict__ counts, const int* __restrict__ bucketBase, int A)
{
    __shared__ int sh[256];
    int b = blockIdx.x, t = threadIdx.x;
    int run = bucketBase[b];
    for (int base = 0; base < A; base += 256) {
        int idx = base + t;
        int v = (idx < A) ? counts[(size_t)b * A + idx] : 0;
        sh[t] = v; __syncthreads();
        for (int d = 1; d < 256; d <<= 1) {
            int add = (t >= d) ? sh[t - d] : 0;
            __syncthreads();
            sh[t] += add;
            __syncthreads();
        }
        if (idx < A) counts[(size_t)b * A + idx] = run + sh[t] - v;
        run += sh[255];
        __syncthreads();
    }
}

// Phase 3: place packed (dstLocal<<23 | src) into bucket-contiguous binned[].
// Valid while nNodes < 2^23 (src field) — N=100000 here.
__global__ __launch_bounds__(256) void k_bin(
    const int* __restrict__ src, const int* __restrict__ dst,
    const int* __restrict__ counts, unsigned int* __restrict__ binned,
    int nEdges, int NB)
{
    __shared__ int cur[256];
    int t = threadIdx.x;
    if (t < NB) cur[t] = counts[t * gridDim.x + blockIdx.x];
    __syncthreads();
    long long base = (long long)blockIdx.x * EPB;
    #pragma unroll
    for (int k = 0; k < EPB / 256; ++k) {
        long long e = base + k * 256 + t;
        if (e < nEdges) {
            int s = src[e], d = dst[e];
            int pos = atomicAdd(&cur[d >> BUCKET_SHIFT], 1);
            binned[pos] = (((unsigned int)(d & (BUCKET_SZ - 1))) << 23) | (unsigned int)s;
        }
    }
}

// Phase 4: per-bucket local CSR: LDS deg hist -> LDS scan -> rowptr + eidx.
__global__ __launch_bounds__(256) void k_localcsr(
    const unsigned int* __restrict__ binned, const int* __restrict__ bucketBase,
    int* __restrict__ rowptr, int* __restrict__ eidx, int nNodes)
{
    __shared__ int ldeg[BUCKET_SZ];
    __shared__ int lscan[256];
    int t = threadIdx.x;
    ldeg[t] = 0; ldeg[t + 256] = 0;
    __syncthreads();
    int eb0 = bucketBase[blockIdx.x], eb1 = bucketBase[blockIdx.x + 1];
    int node0 = blockIdx.x << BUCKET_SHIFT;
    for (int e = eb0 + t; e < eb1; e += 256) {
        atomicAdd(&ldeg[binned[e] >> 23], 1);
    }
    __syncthreads();
    int d0 = ldeg[2 * t], d1 = ldeg[2 * t + 1];
    int s = d0 + d1;
    lscan[t] = s;
    __syncthreads();
    for (int d = 1; d < 256; d <<= 1) {
        int add = (t >= d) ? lscan[t - d] : 0;
        __syncthreads();
        lscan[t] += add;
        __syncthreads();
    }
    int excl = lscan[t] - s;
    ldeg[2 * t]     = excl;        // becomes local cursor
    ldeg[2 * t + 1] = excl + d0;
    int n0 = node0 + 2 * t;
    if (n0 < nNodes)     rowptr[n0]     = eb0 + excl;
    if (n0 + 1 < nNodes) rowptr[n0 + 1] = eb0 + excl + d0;
    __syncthreads();
    for (int e = eb0 + t; e < eb1; e += 256) {
        unsigned int p = binned[e];
        int pos = atomicAdd(&ldeg[p >> 23], 1);
        eidx[eb0 + pos] = (int)(p & 0x7FFFFFu);
    }
}

// ---- Weight swizzle: fp32 W -> bf16 in B-fragment order -----------------
__global__ __launch_bounds__(256) void k_wconv(
    const float* __restrict__ W1, const float* __restrict__ W2,
    unsigned short* __restrict__ w1s, unsigned short* __restrict__ w2s)
{
    int idx = blockIdx.x * blockDim.x + threadIdx.x;
    if (idx < IN_F * HID_F) {            // W1: 16 ntiles x 4 ksteps
        int c = idx >> 9, L = (idx >> 3) & 63, j = idx & 7;
        int ntile = c >> 2, kstep = c & 3;
        int k = kstep * 32 + (L >> 4) * 8 + j;
        int n = ntile * 16 + (L & 15);
        w1s[idx] = f2bf(W1[k * HID_F + n]);
    }
    if (idx < HID_F * OUT_F) {           // W2: 4 ntiles x 8 ksteps
        int c = idx >> 9, L = (idx >> 3) & 63, j = idx & 7;
        int ntile = c >> 3, kstep = c & 7;
        int k = kstep * 32 + (L >> 4) * 8 + j;
        int n = ntile * 16 + (L & 15);
        w2s[idx] = f2bf(W2[k * OUT_F + n]);
    }
}

// ---- Layer-1 gather, XCD-affine feature-chunked -------------------------
// chunk = blockIdx & 7 -> 16 bf16 features (32 B); per-XCD xb slice = 3.2 MB.
// Wave = 8 edge-slots x 8 feature-lanes; 16 edges in flight (2-slot unroll).
__global__ __launch_bounds__(256) void gather1c(
    const unsigned short* __restrict__ xb, const int* __restrict__ rowptr,
    const int* __restrict__ eidx, unsigned short* __restrict__ agg, int nNodes)
{
    int chunk = blockIdx.x & 7;
    int n = (blockIdx.x >> 3) * 4 + (threadIdx.x >> 6);
    if (n >= nNodes) return;
    int lane = threadIdx.x & 63;
    int fl = lane & 7;          // feature sub-lane (uint granularity: 2 bf16)
    int es = lane >> 3;         // edge slot 0..7
    const unsigned int* xc = reinterpret_cast<const unsigned int*>(xb) + chunk * 8 + fl;
    int beg = rowptr[n], end = rowptr[n + 1];
    float ax = 0.f, ay = 0.f;
    for (int base = beg; base < end; base += 16) {
        int e0 = base + es, e1 = base + 8 + es;
        if (e0 < end) {
            unsigned int v = xc[(size_t)eidx[e0] * 64];
            ax += bf2f_lo(v); ay += bf2f_hi(v);
        }
        if (e1 < end) {
            unsigned int v = xc[(size_t)eidx[e1] * 64];
            ax += bf2f_lo(v); ay += bf2f_hi(v);
        }
    }
    // reduce across the 8 edge slots (lane distance 8,16,32)
    ax += __shfl_xor(ax, 8);  ay += __shfl_xor(ay, 8);
    ax += __shfl_xor(ax, 16); ay += __shfl_xor(ay, 16);
    ax += __shfl_xor(ax, 32); ay += __shfl_xor(ay, 32);
    if (es == 0) {
        unsigned int self = xc[(size_t)n * 64];
        ax += bf2f_lo(self); ay += bf2f_hi(self);
        unsigned int p = (unsigned int)f2bf(ax) | ((unsigned int)f2bf(ay) << 16);
        reinterpret_cast<unsigned int*>(agg)[(size_t)n * 64 + chunk * 8 + fl] = p;
    }
}

// ---- GEMM1 (MFMA): h1[M,256] = agg[M,128] @ W1, bf16 out ----------------
__global__ __launch_bounds__(256) void gemm1_mfma(
    const unsigned short* __restrict__ agg, const unsigned short* __restrict__ w1s,
    unsigned short* __restrict__ h1, int nNodes)
{
    int wave = threadIdx.x >> 6, lane = threadIdx.x & 63;
    int m0 = blockIdx.x * 64 + wave * 16;
    if (m0 >= nNodes) return;
    int row = lane & 15, quad = lane >> 4;
    f32x4 acc[16] = {};
    const bf16x8* aBase = reinterpret_cast<const bf16x8*>(
        agg + (size_t)(m0 + row) * IN_F + quad * 8);
    const bf16x8* bBase = reinterpret_cast<const bf16x8*>(w1s) + lane;
    #pragma unroll
    for (int ks = 0; ks < 4; ++ks) {
        bf16x8 a = aBase[ks * 4];
        #pragma unroll
        for (int nt = 0; nt < 16; ++nt) {
            bf16x8 b = bBase[(nt * 4 + ks) * 64];
            acc[nt] = __builtin_amdgcn_mfma_f32_16x16x32_bf16(a, b, acc[nt], 0, 0, 0);
        }
    }
    size_t outBase = (size_t)(m0 + quad * 4) * HID_F + row;
    #pragma unroll
    for (int i = 0; i < 4; ++i) {
        if (m0 + quad * 4 + i >= nNodes) break;   // tail guard
        #pragma unroll
        for (int nt = 0; nt < 16; ++nt)
            h1[outBase + (size_t)i * HID_F + nt * 16] = f2bf(acc[nt][i]);
    }
}

// ---- GEMM2 (MFMA): z[M,64] = h1[M,256] @ W2, bf16 out -------------------
__global__ __launch_bounds__(256) void gemm2_mfma(
    const unsigned short* __restrict__ h1, const unsigned short* __restrict__ w2s,
    unsigned short* __restrict__ z, int nNodes)
{
    int wave = threadIdx.x >> 6, lane = threadIdx.x & 63;
    int m0 = blockIdx.x * 64 + wave * 16;
    if (m0 >= nNodes) return;
    int row = lane & 15, quad = lane >> 4;
    f32x4 acc[4] = {};
    const bf16x8* aBase = reinterpret_cast<const bf16x8*>(
        h1 + (size_t)(m0 + row) * HID_F + quad * 8);
    const bf16x8* bBase = reinterpret_cast<const bf16x8*>(w2s) + lane;
    #pragma unroll
    for (int ks = 0; ks < 8; ++ks) {
        bf16x8 a = aBase[ks * 4];
        #pragma unroll
        for (int nt = 0; nt < 4; ++nt) {
            bf16x8 b = bBase[(nt * 8 + ks) * 64];
            acc[nt] = __builtin_amdgcn_mfma_f32_16x16x32_bf16(a, b, acc[nt], 0, 0, 0);
        }
    }
    size_t outBase = (size_t)(m0 + quad * 4) * OUT_F + row;
    #pragma unroll
    for (int i = 0; i < 4; ++i) {
        if (m0 + quad * 4 + i >= nNodes) break;   // tail guard
        #pragma unroll
        for (int nt = 0; nt < 4; ++nt)
            z[outBase + (size_t)i * OUT_F + nt * 16] = f2bf(acc[nt][i]);
    }
}

// ---- Layer-2 gather (commuted), XCD-affine feature-chunked --------------
// chunk = blockIdx & 3 -> 16 bf16 features; per-chunk z slice = 3.2 MB.
__global__ __launch_bounds__(256) void gather2c(
    const unsigned short* __restrict__ z, const int* __restrict__ rowptr,
    const int* __restrict__ eidx, float* __restrict__ out, int nNodes)
{
    int chunk = blockIdx.x & 3;
    int n = (blockIdx.x >> 2) * 4 + (threadIdx.x >> 6);
    if (n >= nNodes) return;
    int lane = threadIdx.x & 63;
    int fl = lane & 7;
    int es = lane >> 3;
    const unsigned int* zc = reinterpret_cast<const unsigned int*>(z) + chunk * 8 + fl;
    int beg = rowptr[n], end = rowptr[n + 1];
    float ax = 0.f, ay = 0.f;
    for (int base = beg; base < end; base += 16) {
        int e0 = base + es, e1 = base + 8 + es;
        if (e0 < end) {
            unsigned int v = zc[(size_t)eidx[e0] * 32];
            ax += bf2f_lo(v); ay += bf2f_hi(v);
        }
        if (e1 < end) {
            unsigned int v = zc[(size_t)eidx[e1] * 32];
            ax += bf2f_lo(v); ay += bf2f_hi(v);
        }
    }
    ax += __shfl_xor(ax, 8);  ay += __shfl_xor(ay, 8);
    ax += __shfl_xor(ax, 16); ay += __shfl_xor(ay, 16);
    ax += __shfl_xor(ax, 32); ay += __shfl_xor(ay, 32);
    if (es == 0) {
        unsigned int self = zc[(size_t)n * 32];
        ax += bf2f_lo(self); ay += bf2f_hi(self);
        float2 o = make_float2(ax, ay);
        *reinterpret_cast<float2*>(out + (size_t)n * OUT_F + chunk * 16 + fl * 2) = o;
    }
}

extern "C" void kernel_launch(void* const* d_in, const int* in_sizes, int n_in,
                              void* d_out, int out_size, void* d_ws, size_t ws_size,
                              hipStream_t stream) {
    const float* x  = (const float*)d_in[0];
    const int* esrc = (const int*)d_in[1];
    const int* edst = (const int*)d_in[2];
    const float* W1 = (const float*)d_in[3];
    const float* W2 = (const float*)d_in[4];
    float* out      = (float*)d_out;

    const int nNodes = in_sizes[0] / IN_F;
    const int nEdges = in_sizes[1];
    const int NB = (nNodes + BUCKET_SZ - 1) / BUCKET_SZ;   // 196 (must be <= 256)
    const int A  = (nEdges + EPB - 1) / EPB;               // 196 binning blocks

    // Workspace (~90.3 MB; 96.7 MB known-safe from R8):
    char* ws = (char*)d_ws;
    const size_t h1_b     = (size_t)nNodes * HID_F * sizeof(unsigned short);
    const size_t aggz_b   = (size_t)nNodes * IN_F * sizeof(unsigned short);
    const size_t binned_b = (size_t)nEdges * sizeof(unsigned int);
    const size_t eidx_b   = (size_t)nEdges * sizeof(int);
    unsigned short* h1  = (unsigned short*)ws;
    unsigned short* xb  = (unsigned short*)ws;                   // alias of h1
    unsigned short* agg = (unsigned short*)(ws + h1_b);
    unsigned short* z   = (unsigned short*)(ws + h1_b);          // alias of agg
    unsigned int* binned = (unsigned int*)(ws + h1_b + aggz_b);
    int* eidx           = (int*)(ws + h1_b + aggz_b + binned_b);
    unsigned short* w1s = (unsigned short*)(ws + h1_b + aggz_b + binned_b + eidx_b);
    unsigned short* w2s = w1s + IN_F * HID_F;
    int* rowptr     = (int*)(w2s + HID_F * OUT_F);
    int* counts     = rowptr + (nNodes + 1);
    int* bucketBase = counts + (size_t)NB * A;
    int* btot       = bucketBase + (NB + 1);

    k_wconv<<<(IN_F * HID_F + 255) / 256, 256, 0, stream>>>(W1, W2, w1s, w2s);

    long long total8 = (long long)nNodes * IN_F / 8;
    k_xconv<<<(int)((total8 + 255) / 256), 256, 0, stream>>>(x, xb, total8);

    k_hist<<<A, 256, 0, stream>>>(edst, counts, nEdges, NB);
    k_btot<<<NB, 256, 0, stream>>>(counts, btot, A);
    k_scanNB<<<1, 256, 0, stream>>>(btot, bucketBase, rowptr, NB, nNodes, nEdges);
    k_cursor<<<NB, 256, 0, stream>>>(counts, bucketBase, A);
    k_bin<<<A, 256, 0, stream>>>(esrc, edst, counts, binned, nEdges, NB);
    k_localcsr<<<NB, 256, 0, stream>>>(binned, bucketBase, rowptr, eidx, nNodes);

    const int g1Blocks = ((nNodes + 3) / 4) * 8;   // chunk = blockIdx & 7
    const int g2Blocks = ((nNodes + 3) / 4) * 4;   // chunk = blockIdx & 3
    const int mBlocks  = (nNodes + 63) / 64;
    gather1c<<<g1Blocks, 256, 0, stream>>>(xb, rowptr, eidx, agg, nNodes);
    gemm1_mfma<<<mBlocks, 256, 0, stream>>>(agg, w1s, h1, nNodes);
    gemm2_mfma<<<mBlocks, 256, 0, stream>>>(h1, w2s, z, nNodes);
    gather2c<<<g2Blocks, 256, 0, stream>>>(z, rowptr, eidx, out, nNodes);
}